// Round 1
// baseline (806.687 us; speedup 1.0000x reference)
//
#include <hip/hip_runtime.h>
#include <math.h>

#define ORISIZE 256
#define KER 32
#define P 225            // ORISIZE - KER + 1
#define PP (P * P)       // 50625
#define HALF 16          // KER/2
#define FEPS 1e-5f

// ---------------------------------------------------------------------------
// Stage 1: softmax (axis=1, 2 channels) + entropy, fused with horizontal
// 32-wide sliding-window sum. One block per (b, y) row.
//   Hp[b][y][px] = sum_{dx=0..31} p0[b][y][px+dx]
//   He[b][y][px] = sum_{dx=0..31} (ent0+ent1)[b][y][px+dx]
// ---------------------------------------------------------------------------
__global__ __launch_bounds__(256) void field_hpool_kernel(
    const float* __restrict__ infeat, float* __restrict__ Hp,
    float* __restrict__ He) {
  int b = blockIdx.x >> 8;
  int y = blockIdx.x & 255;
  int x = threadIdx.x;

  __shared__ float sp[ORISIZE];
  __shared__ float se[ORISIZE];

  const float* r0 = infeat + ((size_t)(b * 2 + 0) * ORISIZE + y) * ORISIZE;
  const float* r1 = infeat + ((size_t)(b * 2 + 1) * ORISIZE + y) * ORISIZE;
  float a0 = r0[x];
  float a1 = r1[x];
  float m = fmaxf(a0, a1);
  float e0 = expf(a0 - m);
  float e1 = expf(a1 - m);
  float s = e0 + e1;
  float p0 = e0 / s;
  float p1 = e1 / s;
  float ent = -(p0 * logf(p0 + FEPS)) - (p1 * logf(p1 + FEPS));
  sp[x] = p0;
  se[x] = ent;
  __syncthreads();

  if (x < P) {
    float accp = 0.f, acce = 0.f;
#pragma unroll
    for (int dx = 0; dx < KER; ++dx) {
      accp += sp[x + dx];
      acce += se[x + dx];
    }
    size_t o = ((size_t)b * ORISIZE + y) * P + x;
    Hp[o] = accp;
    He[o] = acce;
  }
}

// ---------------------------------------------------------------------------
// Stage 2: vertical 32-tall sliding sum -> pooled averages.
//   SP[b][py][px] = avgpool(p0),  EP[b][py][px] = avgpool(ent0)+avgpool(ent1)
// Thread per output element; column reads are coalesced across px.
// ---------------------------------------------------------------------------
__global__ __launch_bounds__(256) void vpool_kernel(
    const float* __restrict__ Hp, const float* __restrict__ He,
    float* __restrict__ SP, float* __restrict__ EP, int total) {
  int idx = blockIdx.x * blockDim.x + threadIdx.x;
  if (idx >= total) return;
  int b = idx / PP;
  int r = idx - b * PP;
  int py = r / P;
  int px = r - py * P;
  const float* hp = Hp + ((size_t)b * ORISIZE + py) * P + px;
  const float* he = He + ((size_t)b * ORISIZE + py) * P + px;
  float a = 0.f, e = 0.f;
#pragma unroll
  for (int dy = 0; dy < KER; ++dy) {
    a += hp[(size_t)dy * P];
    e += he[(size_t)dy * P];
  }
  SP[idx] = a * (1.f / (KER * KER));
  EP[idx] = e * (1.f / (KER * KER));
}

// ---------------------------------------------------------------------------
// Stage 3: greedy top-k argmax with box suppression, one block per (b, c).
// Exactly replicates reference semantics:
//   filt = (featP_c - 0.1*entP) * mask   (masked entries are EXACTLY 0.0)
//   argmax ties -> smallest flat index (py*225 + px)
// Writes provalue and pointXY directly; records (py,px) for the gather stage.
// ---------------------------------------------------------------------------
__global__ __launch_bounds__(256) void select_kernel(
    const float* __restrict__ SP, const float* __restrict__ EP, int B, int K,
    float* __restrict__ out_val, float* __restrict__ out_xy,
    int* __restrict__ selyx) {
  int bc = blockIdx.x;
  int b = bc % B;
  int c = bc / B;
  int tid = threadIdx.x;

  __shared__ float rv[256];
  __shared__ int ri[256];
  __shared__ int bys[16], bxs[16];

  const float* sp = SP + (size_t)b * PP;
  const float* ep = EP + (size_t)b * PP;

  for (int kk = 0; kk < K; ++kk) {
    float best = -INFINITY;
    int bi = PP;
    for (int i = tid; i < PP; i += 256) {
      int py = i / P;
      int px = i - py * P;
      float sv = sp[i];
      float ev = ep[i];
      float v = ((c == 0) ? sv : 1.0f - sv) - 0.1f * ev;
      bool masked = false;
      for (int j = 0; j < kk; ++j) {
        // clipping to [0,P) is implied by py,px in [0,P)
        if (py >= bys[j] - HALF && py < bys[j] + HALF && px >= bxs[j] - HALF &&
            px < bxs[j] + HALF)
          masked = true;
      }
      if (masked) v = 0.0f;  // mask-multiply semantics, NOT -inf
      if (v > best) {        // strict > keeps earliest index per thread
        best = v;
        bi = i;
      }
    }
    rv[tid] = best;
    ri[tid] = bi;
    __syncthreads();
    for (int sh = 128; sh > 0; sh >>= 1) {
      if (tid < sh) {
        float v2 = rv[tid + sh];
        int i2 = ri[tid + sh];
        if (v2 > rv[tid] || (v2 == rv[tid] && i2 < ri[tid])) {
          rv[tid] = v2;
          ri[tid] = i2;
        }
      }
      __syncthreads();
    }
    if (tid == 0) {
      int idx = ri[0];
      int py = idx / P;
      int px = idx - py * P;
      bys[kk] = py;
      bxs[kk] = px;
      int slot = (c * K + kk) * B + b;
      out_val[slot] = rv[0];
      out_xy[slot * 4 + 0] = (float)px;
      out_xy[slot * 4 + 1] = (float)(px + KER - 1);
      out_xy[slot * 4 + 2] = (float)py;
      out_xy[slot * 4 + 3] = (float)(py + KER - 1);
      selyx[slot * 2 + 0] = py;
      selyx[slot * 2 + 1] = px;
    }
    __syncthreads();
  }
}

// ---------------------------------------------------------------------------
// Stage 4: gather 32x32 patches at selected (py,px) for one source tensor.
// Thread per output element; 32-float rows give 128B contiguous reads.
// ---------------------------------------------------------------------------
__global__ __launch_bounds__(256) void extract_kernel(
    const float* __restrict__ src, float* __restrict__ dst,
    const int* __restrict__ selyx, int Csrc, int B, int total) {
  int idx = blockIdx.x * blockDim.x + threadIdx.x;
  if (idx >= total) return;
  int per = Csrc * KER * KER;
  int slot = idx / per;
  int r = idx - slot * per;
  int ch = r / (KER * KER);
  int rr = r - ch * (KER * KER);
  int dy = rr >> 5;
  int dx = rr & 31;
  int b = slot % B;
  int py = selyx[slot * 2 + 0];
  int px = selyx[slot * 2 + 1];
  dst[idx] =
      src[(((size_t)b * Csrc + ch) * ORISIZE + (py + dy)) * ORISIZE + (px + dx)];
}

extern "C" void kernel_launch(void* const* d_in, const int* in_sizes, int n_in,
                              void* d_out, int out_size, void* d_ws,
                              size_t ws_size, hipStream_t stream) {
  const float* infeat = (const float*)d_in[0];
  const float* labelTpesudo = (const float*)d_in[1];
  const float* labelT = (const float*)d_in[2];
  const float* FeatureDA = (const float*)d_in[3];

  int B = in_sizes[0] / (2 * ORISIZE * ORISIZE);                 // 32
  int C = in_sizes[3] / (B * ORISIZE * ORISIZE);                 // 64
  // out_size = 2*K*B*((C+4)*1024 + 5)  ->  recover K on host
  long per_patch = (long)(C + 4) * KER * KER + 5;
  int K = (int)((long)out_size / (2L * B * per_patch));
  if (K < 1) K = 1;
  if (K > 16) K = 16;
  int npatch = 2 * K * B;

  // workspace layout
  float* Hp = (float*)d_ws;
  float* He = Hp + (size_t)B * ORISIZE * P;
  float* SP = He + (size_t)B * ORISIZE * P;
  float* EP = SP + (size_t)B * PP;
  int* selyx = (int*)(EP + (size_t)B * PP);

  // output layout (floats), concatenated in reference return order
  float* out = (float*)d_out;
  size_t o_cls = 0;
  size_t o_feat = o_cls + (size_t)npatch * 2 * KER * KER;
  size_t o_lp = o_feat + (size_t)npatch * C * KER * KER;
  size_t o_lt = o_lp + (size_t)npatch * 1 * KER * KER;
  size_t o_val = o_lt + (size_t)npatch * 1 * KER * KER;
  size_t o_xy = o_val + (size_t)npatch;

  field_hpool_kernel<<<dim3(B * ORISIZE), dim3(256), 0, stream>>>(infeat, Hp,
                                                                  He);

  int totalv = B * PP;
  vpool_kernel<<<dim3((totalv + 255) / 256), dim3(256), 0, stream>>>(
      Hp, He, SP, EP, totalv);

  select_kernel<<<dim3(2 * B), dim3(256), 0, stream>>>(
      SP, EP, B, K, out + o_val, out + o_xy, selyx);

  int t_cls = npatch * 2 * KER * KER;
  extract_kernel<<<dim3((t_cls + 255) / 256), dim3(256), 0, stream>>>(
      infeat, out + o_cls, selyx, 2, B, t_cls);
  int t_feat = npatch * C * KER * KER;
  extract_kernel<<<dim3((t_feat + 255) / 256), dim3(256), 0, stream>>>(
      FeatureDA, out + o_feat, selyx, C, B, t_feat);
  int t_lab = npatch * 1 * KER * KER;
  extract_kernel<<<dim3((t_lab + 255) / 256), dim3(256), 0, stream>>>(
      labelTpesudo, out + o_lp, selyx, 1, B, t_lab);
  extract_kernel<<<dim3((t_lab + 255) / 256), dim3(256), 0, stream>>>(
      labelT, out + o_lt, selyx, 1, B, t_lab);
}

// Round 2
// 707.458 us; speedup vs baseline: 1.1403x; 1.1403x over previous
//
#include <hip/hip_runtime.h>
#include <math.h>

#define ORISIZE 256
#define KER 32
#define P 225            // ORISIZE - KER + 1
#define PP (P * P)       // 50625
#define HALF 16          // KER/2
#define FEPS 1e-5f
#define NSPLIT 32        // argmax parallel splits per (b,c)
#define CHUNK ((PP + NSPLIT - 1) / NSPLIT)  // 1583

// ---------------------------------------------------------------------------
// Stage 1: softmax (axis=1, 2 channels) + entropy, fused with horizontal
// 32-wide sliding-window sum. One block per (b, y) row.
// ---------------------------------------------------------------------------
__global__ __launch_bounds__(256) void field_hpool_kernel(
    const float* __restrict__ infeat, float* __restrict__ Hp,
    float* __restrict__ He) {
  int b = blockIdx.x >> 8;
  int y = blockIdx.x & 255;
  int x = threadIdx.x;

  __shared__ float sp[ORISIZE];
  __shared__ float se[ORISIZE];

  const float* r0 = infeat + ((size_t)(b * 2 + 0) * ORISIZE + y) * ORISIZE;
  const float* r1 = infeat + ((size_t)(b * 2 + 1) * ORISIZE + y) * ORISIZE;
  float a0 = r0[x];
  float a1 = r1[x];
  float m = fmaxf(a0, a1);
  float e0 = expf(a0 - m);
  float e1 = expf(a1 - m);
  float s = e0 + e1;
  float p0 = e0 / s;
  float p1 = e1 / s;
  float ent = -(p0 * logf(p0 + FEPS)) - (p1 * logf(p1 + FEPS));
  sp[x] = p0;
  se[x] = ent;
  __syncthreads();

  if (x < P) {
    float accp = 0.f, acce = 0.f;
#pragma unroll
    for (int dx = 0; dx < KER; ++dx) {
      accp += sp[x + dx];
      acce += se[x + dx];
    }
    size_t o = ((size_t)b * ORISIZE + y) * P + x;
    Hp[o] = accp;
    He[o] = acce;
  }
}

// ---------------------------------------------------------------------------
// Stage 2: vertical 32-tall sliding sum -> final filter fields directly.
//   sv = avgpool(p0); ev = avgpool(ent)
//   F[0][b][i] = sv - 0.1*ev          (class 0 filter, unmasked)
//   F[1][b][i] = (1 - sv) - 0.1*ev    (class 1 filter, unmasked)
// Exact same float op sequence as the verified round-1 kernel (absmax 0.0).
// ---------------------------------------------------------------------------
__global__ __launch_bounds__(256) void vpool_kernel(
    const float* __restrict__ Hp, const float* __restrict__ He,
    float* __restrict__ F, int B, int total) {
  int idx = blockIdx.x * blockDim.x + threadIdx.x;
  if (idx >= total) return;
  int b = idx / PP;
  int r = idx - b * PP;
  int py = r / P;
  int px = r - py * P;
  const float* hp = Hp + ((size_t)b * ORISIZE + py) * P + px;
  const float* he = He + ((size_t)b * ORISIZE + py) * P + px;
  float a = 0.f, e = 0.f;
#pragma unroll
  for (int dy = 0; dy < KER; ++dy) {
    a += hp[(size_t)dy * P];
    e += he[(size_t)dy * P];
  }
  float sv = a * (1.f / (KER * KER));
  float ev = e * (1.f / (KER * KER));
  F[(size_t)(0 * B + b) * PP + r] = sv - 0.1f * ev;
  F[(size_t)(1 * B + b) * PP + r] = (1.0f - sv) - 0.1f * ev;
}

// ---------------------------------------------------------------------------
// Stage 3a: one suppression round, parallel. grid = (NSPLIT, B, 2).
// Each block first (redundantly, cheaply) reconstructs the boxes of rounds
// j<kk by reducing their partials, then scans its contiguous chunk with
// mask-multiply semantics (masked -> exactly 0.0) and writes one partial
// (val, idx) with reference tie-breaking (max val, then smallest flat idx).
// ---------------------------------------------------------------------------
__global__ __launch_bounds__(256) void argmax_round_kernel(
    const float* __restrict__ F, float* __restrict__ pval,
    int* __restrict__ pidx, int B, int kk) {
  int s = blockIdx.x;
  int b = blockIdx.y;
  int c = blockIdx.z;
  int tid = threadIdx.x;

  __shared__ int bys[16], bxs[16];
  __shared__ float rv[256];
  __shared__ int ri[256];

  if (tid < kk) {  // kk <= 16: one thread per prior round
    int j = tid;
    int pbase = ((j * B + b) * 2 + c) * NSPLIT;
    float bv = -INFINITY;
    int bi = PP;
    for (int ss = 0; ss < NSPLIT; ++ss) {
      float v = pval[pbase + ss];
      int ii = pidx[pbase + ss];
      if (v > bv || (v == bv && ii < bi)) { bv = v; bi = ii; }
    }
    int py = bi / P;
    bys[j] = py;
    bxs[j] = bi - py * P;
  }
  __syncthreads();

  const float* f = F + ((size_t)c * B + b) * PP;
  int base = s * CHUNK;
  int end = base + CHUNK;
  if (end > PP) end = PP;

  float best = -INFINITY;
  int bi = PP;
  for (int i = base + tid; i < end; i += 256) {
    float v = f[i];
    int py = i / P;
    int px = i - py * P;
    bool masked = false;
    for (int j = 0; j < kk; ++j) {
      if (py >= bys[j] - HALF && py < bys[j] + HALF && px >= bxs[j] - HALF &&
          px < bxs[j] + HALF)
        masked = true;
    }
    if (masked) v = 0.0f;  // mask-multiply, NOT -inf
    if (v > best) {        // strict > keeps earliest index per thread
      best = v;
      bi = i;
    }
  }
  rv[tid] = best;
  ri[tid] = bi;
  __syncthreads();
  for (int sh = 128; sh > 0; sh >>= 1) {
    if (tid < sh) {
      float v2 = rv[tid + sh];
      int i2 = ri[tid + sh];
      if (v2 > rv[tid] || (v2 == rv[tid] && i2 < ri[tid])) {
        rv[tid] = v2;
        ri[tid] = i2;
      }
    }
    __syncthreads();
  }
  if (tid == 0) {
    int p = ((kk * B + b) * 2 + c) * NSPLIT + s;
    pval[p] = rv[0];
    pidx[p] = ri[0];
  }
}

// ---------------------------------------------------------------------------
// Stage 3b: final reduce of all rounds' partials -> provalue, pointXY, selyx.
// One thread per (kk, b, c); B*2*K <= 256 for K<=4 (grid-stride for safety).
// ---------------------------------------------------------------------------
__global__ __launch_bounds__(256) void finish_kernel(
    const float* __restrict__ pval, const int* __restrict__ pidx, int B, int K,
    float* __restrict__ out_val, float* __restrict__ out_xy,
    int* __restrict__ selyx) {
  int total = B * 2 * K;
  for (int t = blockIdx.x * blockDim.x + threadIdx.x; t < total;
       t += gridDim.x * blockDim.x) {
    int c = t & 1;
    int rem = t >> 1;
    int b = rem % B;
    int kk = rem / B;
    int pbase = ((kk * B + b) * 2 + c) * NSPLIT;
    float bv = -INFINITY;
    int bi = PP;
    for (int ss = 0; ss < NSPLIT; ++ss) {
      float v = pval[pbase + ss];
      int ii = pidx[pbase + ss];
      if (v > bv || (v == bv && ii < bi)) { bv = v; bi = ii; }
    }
    int py = bi / P;
    int px = bi - py * P;
    int slot = (c * K + kk) * B + b;
    out_val[slot] = bv;
    out_xy[slot * 4 + 0] = (float)px;
    out_xy[slot * 4 + 1] = (float)(px + KER - 1);
    out_xy[slot * 4 + 2] = (float)py;
    out_xy[slot * 4 + 3] = (float)(py + KER - 1);
    selyx[slot * 2 + 0] = py;
    selyx[slot * 2 + 1] = px;
  }
}

// ---------------------------------------------------------------------------
// Stage 4: single fused gather for all four patch tensors.
// Channel plane tc in [0, C+4): 0-1 -> infeat, 2..C+1 -> FeatureDA,
// C+2 -> labelTpesudo, C+3 -> labelT. 32-float rows = 128B contiguous reads.
// ---------------------------------------------------------------------------
__global__ __launch_bounds__(256) void extract_all_kernel(
    const float* __restrict__ infeat, const float* __restrict__ FeatureDA,
    const float* __restrict__ lp, const float* __restrict__ lt,
    const int* __restrict__ selyx, int B, int C, int total,
    float* __restrict__ out, size_t o_feat, size_t o_lp, size_t o_lt) {
  int idx = blockIdx.x * blockDim.x + threadIdx.x;
  if (idx >= total) return;
  int TC = C + 4;
  int per = TC * KER * KER;
  int slot = idx / per;
  int rem = idx - slot * per;
  int tc = rem >> 10;   // / 1024
  int pix = rem & 1023;
  int dy = pix >> 5;
  int dx = pix & 31;
  int b = slot % B;
  int py = selyx[slot * 2 + 0];
  int px = selyx[slot * 2 + 1];

  const float* src;
  int ch, srcC;
  size_t dsto;
  if (tc < 2) {
    src = infeat; ch = tc; srcC = 2;
    dsto = ((size_t)slot * 2 + ch) * 1024;
  } else if (tc < 2 + C) {
    src = FeatureDA; ch = tc - 2; srcC = C;
    dsto = o_feat + ((size_t)slot * C + ch) * 1024;
  } else if (tc == 2 + C) {
    src = lp; ch = 0; srcC = 1;
    dsto = o_lp + (size_t)slot * 1024;
  } else {
    src = lt; ch = 0; srcC = 1;
    dsto = o_lt + (size_t)slot * 1024;
  }
  out[dsto + pix] =
      src[(((size_t)b * srcC + ch) * ORISIZE + (py + dy)) * ORISIZE + (px + dx)];
}

extern "C" void kernel_launch(void* const* d_in, const int* in_sizes, int n_in,
                              void* d_out, int out_size, void* d_ws,
                              size_t ws_size, hipStream_t stream) {
  const float* infeat = (const float*)d_in[0];
  const float* labelTpesudo = (const float*)d_in[1];
  const float* labelT = (const float*)d_in[2];
  const float* FeatureDA = (const float*)d_in[3];

  int B = in_sizes[0] / (2 * ORISIZE * ORISIZE);  // 32
  int C = in_sizes[3] / (B * ORISIZE * ORISIZE);  // 64
  long per_patch = (long)(C + 4) * KER * KER + 5;
  int K = (int)((long)out_size / (2L * B * per_patch));
  if (K < 1) K = 1;
  if (K > 16) K = 16;
  int npatch = 2 * K * B;

  // workspace layout
  float* Hp = (float*)d_ws;
  float* He = Hp + (size_t)B * ORISIZE * P;
  float* F = He + (size_t)B * ORISIZE * P;          // [2][B][PP]
  float* pval = F + (size_t)2 * B * PP;             // [K][B][2][NSPLIT]
  int* pidx = (int*)(pval + (size_t)16 * B * 2 * NSPLIT);
  int* selyx = pidx + (size_t)16 * B * 2 * NSPLIT;  // [npatch][2]

  // output layout (floats), concatenated in reference return order
  float* out = (float*)d_out;
  size_t o_feat = (size_t)npatch * 2 * KER * KER;
  size_t o_lp = o_feat + (size_t)npatch * C * KER * KER;
  size_t o_lt = o_lp + (size_t)npatch * KER * KER;
  size_t o_val = o_lt + (size_t)npatch * KER * KER;
  size_t o_xy = o_val + (size_t)npatch;

  field_hpool_kernel<<<dim3(B * ORISIZE), dim3(256), 0, stream>>>(infeat, Hp,
                                                                  He);

  int totalv = B * PP;
  vpool_kernel<<<dim3((totalv + 255) / 256), dim3(256), 0, stream>>>(
      Hp, He, F, B, totalv);

  for (int kk = 0; kk < K; ++kk) {
    argmax_round_kernel<<<dim3(NSPLIT, B, 2), dim3(256), 0, stream>>>(
        F, pval, pidx, B, kk);
  }
  finish_kernel<<<dim3(1), dim3(256), 0, stream>>>(pval, pidx, B, K,
                                                   out + o_val, out + o_xy,
                                                   selyx);

  int total = npatch * (C + 4) * KER * KER;
  extract_all_kernel<<<dim3((total + 255) / 256), dim3(256), 0, stream>>>(
      infeat, FeatureDA, labelTpesudo, labelT, selyx, B, C, total, out, o_feat,
      o_lp, o_lt);
}